// Round 11
// baseline (315.776 us; speedup 1.0000x reference)
//
#include <hip/hip_runtime.h>

// GraphSAGE 2-layer, N=100000, E=1600000, 128 -> 64 -> 32.
// Round 11: fill_csr chunk mapping XCD-aligned. Round-10 counters proved the
// dst-chunked fill did NOT merge writes (WRITE_SIZE still 107MB = 64B/edge):
// chunk blocks were spread over all 8 XCDs, so the same csr lines were dirty
// in 8 non-coherent L2s. blockIdx round-robins XCDs -> chunk = blockIdx & 7
// puts a chunk's 128 blocks on ONE XCD; its 800KB window merges in that L2.
// All other kernels byte-identical to round 10.

namespace {
constexpr int N = 100000;
constexpr int E = 1600000;
constexpr long long NF64 = (long long)N * 64;   // 6,400,000
constexpr long long NF32 = (long long)N * 32;
constexpr int NBLK = (N + 255) / 256;           // 391 scan blocks
constexpr int NT16 = N / 16;                    // 6250 node tiles (exact)
constexpr int NCHUNK = 8;                       // 12500 nodes per chunk
constexpr int CHUNK_N = N / NCHUNK;
constexpr int BPC = 128;                        // blocks per chunk
}

using bf16x8 = __attribute__((ext_vector_type(8))) short;
using f32x4  = __attribute__((ext_vector_type(4))) float;

__device__ __forceinline__ short f2bf(float f) {
    unsigned u = __builtin_bit_cast(unsigned, f);
    u += 0x7FFFu + ((u >> 16) & 1u);            // RNE truncate to bf16
    return (short)(u >> 16);
}

__device__ __forceinline__ bf16x8 load_frag8(const float* __restrict__ p) {
    const float4* p4 = (const float4*)p;
    float4 f0 = p4[0], f1 = p4[1];
    bf16x8 r;
    r[0] = f2bf(f0.x); r[1] = f2bf(f0.y); r[2] = f2bf(f0.z); r[3] = f2bf(f0.w);
    r[4] = f2bf(f1.x); r[5] = f2bf(f1.y); r[6] = f2bf(f1.z); r[7] = f2bf(f1.w);
    return r;
}

// ---------------- CSR build ----------------

// int64 vs int32 edge dtype: sample 16384 high words, single block, one store.
__global__ __launch_bounds__(256) void detect_dtype(const int* __restrict__ raw,
                                                    int* __restrict__ flag) {
    int any = 0;
#pragma unroll
    for (int k = 0; k < 64; ++k) {
        int i = threadIdx.x + k * 256;          // first 16384 qwords
        any |= raw[2 * i + 1];
    }
    unsigned long long b = __ballot(any != 0);
    __shared__ int acc[4];
    int w = threadIdx.x >> 6;
    if ((threadIdx.x & 63) == 0) acc[w] = (b != 0ULL) ? 1 : 0;
    __syncthreads();
    if (threadIdx.x == 0) *flag = acc[0] | acc[1] | acc[2] | acc[3];
}

__global__ void zero_counts(int* __restrict__ counts) {
    int i = blockIdx.x * blockDim.x + threadIdx.x;
    if (i < N) counts[i] = 0;
}

__global__ void count_deg(const int* __restrict__ raw, const int* __restrict__ flag,
                          int* __restrict__ counts) {
    int e = blockIdx.x * blockDim.x + threadIdx.x;
    if (e >= E) return;
    int is32 = *flag;
    int d = is32 ? raw[E + e] : raw[2 * ((long long)E + e)];
    atomicAdd(&counts[d], 1);
}

// Block-local inclusive scan (Hillis-Steele over 256 entries in LDS).
__global__ __launch_bounds__(256) void scan1(const int* __restrict__ counts,
                                             int* __restrict__ rowstart,
                                             int* __restrict__ bsum) {
    __shared__ int tmp[256];
    int t = threadIdx.x;
    int i = blockIdx.x * 256 + t;
    int v = (i < N) ? counts[i] : 0;
    tmp[t] = v;
    __syncthreads();
#pragma unroll
    for (int off = 1; off < 256; off <<= 1) {
        int a = (t >= off) ? tmp[t - off] : 0;
        __syncthreads();
        tmp[t] += a;
        __syncthreads();
    }
    if (i < N) rowstart[i] = tmp[t] - v;          // exclusive within block
    if (t == 255) bsum[blockIdx.x] = tmp[255];    // block total
}

__global__ __launch_bounds__(512) void scan2(int* __restrict__ bsum) {
    __shared__ int tmp[512];
    int t = threadIdx.x;
    int v = (t < NBLK) ? bsum[t] : 0;
    tmp[t] = v;
    __syncthreads();
#pragma unroll
    for (int off = 1; off < 512; off <<= 1) {
        int a = (t >= off) ? tmp[t - off] : 0;
        __syncthreads();
        tmp[t] += a;
        __syncthreads();
    }
    if (t < NBLK) bsum[t] = tmp[t] - v;           // exclusive block offsets
}

__global__ void scan3(int* __restrict__ rowstart, const int* __restrict__ bsum,
                      int* __restrict__ cursor) {
    int i = blockIdx.x * blockDim.x + threadIdx.x;
    if (i < N) {
        rowstart[i] += bsum[i >> 8];
        cursor[i] = 0;                            // counts recycled as cursor
    }
    if (i == 0) rowstart[N] = E;
}

// Dst-chunked CSR fill, XCD-aligned: chunk = blockIdx & 7 so all blocks of a
// chunk dispatch to the same XCD (round-robin mapping); the chunk's ~800KB
// csr window then merges in a single L2 before writeback.
__global__ __launch_bounds__(256) void fill_csr_chunked(
        const int* __restrict__ raw, const int* __restrict__ flag,
        const int* __restrict__ rowstart, int* __restrict__ cursor,
        int* __restrict__ csr) {
    const int chunk = blockIdx.x & (NCHUNK - 1);
    const int bsl   = blockIdx.x >> 3;
    const int lo = chunk * CHUNK_N, hi = lo + CHUNK_N;
    const int is32 = *flag;
    for (int e = bsl * 256 + threadIdx.x; e < E; e += BPC * 256) {
        int d = is32 ? raw[E + e] : raw[2 * ((long long)E + e)];
        if (d < lo || d >= hi) continue;
        int s = is32 ? raw[e] : raw[2 * (long long)e];
        int pos = rowstart[d] + atomicAdd(&cursor[d], 1);
        csr[pos] = s;
    }
}

// ---------------- layer 1 transform (MFMA): z1 = x@W1l^T, r1 = x@W1r^T ----------------
__global__ __launch_bounds__(256) void transform1_mfma(
        const float* __restrict__ x, const float* __restrict__ W1l,
        const float* __restrict__ W1r, float* __restrict__ z1,
        float* __restrict__ r1) {
    const int lane = threadIdx.x & 63;
    const int gw = blockIdx.x * 4 + (threadIdx.x >> 6);
    const int q = gw & 1;
    const int r16 = lane & 15;
    const int kgrp = lane >> 4;                  // 0..3

    bf16x8 wf[2][2][4];                          // [mat][coltile][kb]
#pragma unroll
    for (int m = 0; m < 2; ++m) {
        const float* W = m ? W1r : W1l;
#pragma unroll
        for (int c = 0; c < 2; ++c) {
            const float* pw = W + (size_t)(q * 32 + c * 16 + r16) * 128 + kgrp * 8;
#pragma unroll
            for (int kb = 0; kb < 4; ++kb)
                wf[m][c][kb] = load_frag8(pw + kb * 32);
        }
    }

    const int stride = (gridDim.x * 4) >> 1;
    for (int t = gw >> 1; t < NT16; t += stride) {
        const float* px = x + ((size_t)t * 16 + r16) * 128 + kgrp * 8;
        bf16x8 af[4];
#pragma unroll
        for (int kb = 0; kb < 4; ++kb) af[kb] = load_frag8(px + kb * 32);

        f32x4 a00 = {0.f,0.f,0.f,0.f}, a01 = {0.f,0.f,0.f,0.f};
        f32x4 a10 = {0.f,0.f,0.f,0.f}, a11 = {0.f,0.f,0.f,0.f};
#pragma unroll
        for (int kb = 0; kb < 4; ++kb) {
            a00 = __builtin_amdgcn_mfma_f32_16x16x32_bf16(af[kb], wf[0][0][kb], a00, 0, 0, 0);
            a01 = __builtin_amdgcn_mfma_f32_16x16x32_bf16(af[kb], wf[0][1][kb], a01, 0, 0, 0);
            a10 = __builtin_amdgcn_mfma_f32_16x16x32_bf16(af[kb], wf[1][0][kb], a10, 0, 0, 0);
            a11 = __builtin_amdgcn_mfma_f32_16x16x32_bf16(af[kb], wf[1][1][kb], a11, 0, 0, 0);
        }
#pragma unroll
        for (int i = 0; i < 4; ++i) {
            size_t row = (size_t)t * 16 + kgrp * 4 + i;
            z1[row * 64 + q * 32 +  0 + r16] = a00[i];
            z1[row * 64 + q * 32 + 16 + r16] = a01[i];
            r1[row * 64 + q * 32 +  0 + r16] = a10[i];
            r1[row * 64 + q * 32 + 16 + r16] = a11[i];
        }
    }
}

// ---------------- layer 2 transform (MFMA): z2 = h@W2l^T, r2 = h@W2r^T ----------------
__global__ __launch_bounds__(256) void transform2_mfma(
        const float* __restrict__ h, const float* __restrict__ W2l,
        const float* __restrict__ W2r, float* __restrict__ z2,
        float* __restrict__ r2) {
    const int lane = threadIdx.x & 63;
    const int gw = blockIdx.x * 4 + (threadIdx.x >> 6);
    const int r16 = lane & 15;
    const int kgrp = lane >> 4;

    bf16x8 wf[2][2][2];                          // [mat][coltile][kb]
#pragma unroll
    for (int m = 0; m < 2; ++m) {
        const float* W = m ? W2r : W2l;
#pragma unroll
        for (int c = 0; c < 2; ++c) {
            const float* pw = W + (size_t)(c * 16 + r16) * 64 + kgrp * 8;
#pragma unroll
            for (int kb = 0; kb < 2; ++kb)
                wf[m][c][kb] = load_frag8(pw + kb * 32);
        }
    }

    for (int t = gw; t < NT16; t += gridDim.x * 4) {
        const float* ph = h + ((size_t)t * 16 + r16) * 64 + kgrp * 8;
        bf16x8 af[2];
        af[0] = load_frag8(ph);
        af[1] = load_frag8(ph + 32);

        f32x4 a00 = {0.f,0.f,0.f,0.f}, a01 = {0.f,0.f,0.f,0.f};
        f32x4 a10 = {0.f,0.f,0.f,0.f}, a11 = {0.f,0.f,0.f,0.f};
#pragma unroll
        for (int kb = 0; kb < 2; ++kb) {
            a00 = __builtin_amdgcn_mfma_f32_16x16x32_bf16(af[kb], wf[0][0][kb], a00, 0, 0, 0);
            a01 = __builtin_amdgcn_mfma_f32_16x16x32_bf16(af[kb], wf[0][1][kb], a01, 0, 0, 0);
            a10 = __builtin_amdgcn_mfma_f32_16x16x32_bf16(af[kb], wf[1][0][kb], a10, 0, 0, 0);
            a11 = __builtin_amdgcn_mfma_f32_16x16x32_bf16(af[kb], wf[1][1][kb], a11, 0, 0, 0);
        }
#pragma unroll
        for (int i = 0; i < 4; ++i) {
            size_t row = (size_t)t * 16 + kgrp * 4 + i;
            z2[row * 32 +  0 + r16] = a00[i];
            z2[row * 32 + 16 + r16] = a01[i];
            r2[row * 32 +  0 + r16] = a10[i];
            r2[row * 32 + 16 + r16] = a11[i];
        }
    }
}

// ---------------- fused CSR-gather aggregation ----------------

// Layer 1: wave per node, lane = feature j (64 feats).
__global__ __launch_bounds__(256) void agg1_fused(
        const int* __restrict__ rowstart, const int* __restrict__ csr,
        const float* __restrict__ z1, const float* __restrict__ r1,
        const float* __restrict__ b1, float* __restrict__ h) {
    const int n = blockIdx.x * 4 + (threadIdx.x >> 6);
    if (n >= N) return;
    const int j = threadIdx.x & 63;
    const int beg = rowstart[n], end = rowstart[n + 1];
    float s = 0.f;
    int p = beg;
    for (; p + 4 <= end; p += 4) {
        int c0 = csr[p], c1 = csr[p + 1], c2 = csr[p + 2], c3 = csr[p + 3];
        s += z1[(size_t)c0 * 64 + j] + z1[(size_t)c1 * 64 + j]
           + z1[(size_t)c2 * 64 + j] + z1[(size_t)c3 * 64 + j];
    }
    for (; p < end; ++p) s += z1[(size_t)csr[p] * 64 + j];
    float m = (end > beg) ? s / (float)(end - beg) : 0.f;
    size_t o = (size_t)n * 64 + j;
    h[o] = fmaxf(m + b1[j] + r1[o], 0.f);
}

// Layer 2: half-wave per node (32 feats), wave handles 2 nodes.
__global__ __launch_bounds__(256) void agg2_fused(
        const int* __restrict__ rowstart, const int* __restrict__ csr,
        const float* __restrict__ z2, const float* __restrict__ r2,
        const float* __restrict__ b2, float* __restrict__ out) {
    const int wid = blockIdx.x * 4 + (threadIdx.x >> 6);
    const int n = wid * 2 + ((threadIdx.x >> 5) & 1);
    if (n >= N) return;
    const int j = threadIdx.x & 31;
    const int beg = rowstart[n], end = rowstart[n + 1];
    float s = 0.f;
    int p = beg;
    for (; p + 4 <= end; p += 4) {
        int c0 = csr[p], c1 = csr[p + 1], c2 = csr[p + 2], c3 = csr[p + 3];
        s += z2[(size_t)c0 * 32 + j] + z2[(size_t)c1 * 32 + j]
           + z2[(size_t)c2 * 32 + j] + z2[(size_t)c3 * 32 + j];
    }
    for (; p < end; ++p) s += z2[(size_t)csr[p] * 32 + j];
    float m = (end > beg) ? s / (float)(end - beg) : 0.f;
    size_t o = (size_t)n * 32 + j;
    out[o] = m + b2[j] + r2[o];
}

// ---------------- launch ----------------

extern "C" void kernel_launch(void* const* d_in, const int* in_sizes, int n_in,
                              void* d_out, int out_size, void* d_ws, size_t ws_size,
                              hipStream_t stream) {
    const float* x    = (const float*)d_in[0];
    const int*   raw  = (const int*)d_in[1];
    const float* W1l  = (const float*)d_in[2];
    const float* b1   = (const float*)d_in[3];
    const float* W1r  = (const float*)d_in[4];
    const float* W2l  = (const float*)d_in[5];
    const float* b2   = (const float*)d_in[6];
    const float* W2r  = (const float*)d_in[7];
    float* out = (float*)d_out;

    float* ws = (float*)d_ws;
    float* z1 = ws;                    // [N*64]
    float* r1 = ws + NF64;             // [N*64]
    float* h  = ws + 2 * NF64;         // [N*64]
    float* z2 = ws;                    // reuse z1 space [N*32]
    float* r2 = ws + NF32;             // reuse z1 space [N*32]

    int* ibase    = (int*)(ws + 3 * NF64);
    int* counts   = ibase;                   // [N], recycled as cursor
    int* rowstart = ibase + N;               // [N+1]
    int* bsum     = ibase + 2 * N + 1;       // [512]
    int* csr      = ibase + 2 * N + 1 + 512; // [E]
    int* flag     = csr + E;                 // [1]

    const int eb = (E + 255) / 256;

    detect_dtype<<<1, 256, 0, stream>>>(raw, flag);
    zero_counts<<<NBLK, 256, 0, stream>>>(counts);
    count_deg<<<eb, 256, 0, stream>>>(raw, flag, counts);
    scan1<<<NBLK, 256, 0, stream>>>(counts, rowstart, bsum);
    scan2<<<1, 512, 0, stream>>>(bsum);
    scan3<<<NBLK, 256, 0, stream>>>(rowstart, bsum, counts);
    fill_csr_chunked<<<NCHUNK * BPC, 256, 0, stream>>>(raw, flag, rowstart, counts, csr);

    transform1_mfma<<<1024, 256, 0, stream>>>(x, W1l, W1r, z1, r1);
    agg1_fused<<<(N + 3) / 4, 256, 0, stream>>>(rowstart, csr, z1, r1, b1, h);

    transform2_mfma<<<1024, 256, 0, stream>>>(h, W2l, W2r, z2, r2);
    agg2_fused<<<(N + 7) / 8, 256, 0, stream>>>(rowstart, csr, z2, r2, b2, out);
}

// Round 12
// 315.698 us; speedup vs baseline: 1.0002x; 1.0002x over previous
//
#include <hip/hip_runtime.h>

// GraphSAGE 2-layer, N=100000, E=1600000, 128 -> 64 -> 32.
// Round 12 (two levers on top of round 11):
//  1. fill_csr_chunked uses non-temporal loads for the edge stream: round-11
//     counters showed the 12.8MB/pass streaming reads evict the 800KB csr
//     write window from the XCD's L2 before lines fill (WRITE still 72MB).
//     nt loads keep the window resident -> writes merge.
//  2. z1/z2 stored as bf16 (r1/r2/h stay f32): halves the line-granular
//     gather traffic in agg1/agg2 and the z write traffic in transforms.
//     Adds ~one bf16 rounding to the aggregated term; predicted absmax
//     ~0.015 vs threshold 0.0284 (round-11: 0.0078 all-f32-z).
// Everything else byte-identical to round 11.

namespace {
constexpr int N = 100000;
constexpr int E = 1600000;
constexpr long long NF64 = (long long)N * 64;   // 6,400,000
constexpr int NBLK = (N + 255) / 256;           // 391 scan blocks
constexpr int NT16 = N / 16;                    // 6250 node tiles (exact)
constexpr int NCHUNK = 8;                       // 12500 nodes per chunk
constexpr int CHUNK_N = N / NCHUNK;
constexpr int BPC = 128;                        // blocks per chunk
}

using bf16x8 = __attribute__((ext_vector_type(8))) short;
using f32x4  = __attribute__((ext_vector_type(4))) float;

__device__ __forceinline__ short f2bf(float f) {
    unsigned u = __builtin_bit_cast(unsigned, f);
    u += 0x7FFFu + ((u >> 16) & 1u);            // RNE truncate to bf16
    return (short)(u >> 16);
}

__device__ __forceinline__ float bf2f(unsigned short u) {
    return __builtin_bit_cast(float, (unsigned)u << 16);
}

__device__ __forceinline__ bf16x8 load_frag8(const float* __restrict__ p) {
    const float4* p4 = (const float4*)p;
    float4 f0 = p4[0], f1 = p4[1];
    bf16x8 r;
    r[0] = f2bf(f0.x); r[1] = f2bf(f0.y); r[2] = f2bf(f0.z); r[3] = f2bf(f0.w);
    r[4] = f2bf(f1.x); r[5] = f2bf(f1.y); r[6] = f2bf(f1.z); r[7] = f2bf(f1.w);
    return r;
}

// ---------------- CSR build ----------------

// int64 vs int32 edge dtype: sample 16384 high words, single block, one store.
__global__ __launch_bounds__(256) void detect_dtype(const int* __restrict__ raw,
                                                    int* __restrict__ flag) {
    int any = 0;
#pragma unroll
    for (int k = 0; k < 64; ++k) {
        int i = threadIdx.x + k * 256;          // first 16384 qwords
        any |= raw[2 * i + 1];
    }
    unsigned long long b = __ballot(any != 0);
    __shared__ int acc[4];
    int w = threadIdx.x >> 6;
    if ((threadIdx.x & 63) == 0) acc[w] = (b != 0ULL) ? 1 : 0;
    __syncthreads();
    if (threadIdx.x == 0) *flag = acc[0] | acc[1] | acc[2] | acc[3];
}

__global__ void zero_counts(int* __restrict__ counts) {
    int i = blockIdx.x * blockDim.x + threadIdx.x;
    if (i < N) counts[i] = 0;
}

__global__ void count_deg(const int* __restrict__ raw, const int* __restrict__ flag,
                          int* __restrict__ counts) {
    int e = blockIdx.x * blockDim.x + threadIdx.x;
    if (e >= E) return;
    int is32 = *flag;
    int d = is32 ? raw[E + e] : raw[2 * ((long long)E + e)];
    atomicAdd(&counts[d], 1);
}

// Block-local inclusive scan (Hillis-Steele over 256 entries in LDS).
__global__ __launch_bounds__(256) void scan1(const int* __restrict__ counts,
                                             int* __restrict__ rowstart,
                                             int* __restrict__ bsum) {
    __shared__ int tmp[256];
    int t = threadIdx.x;
    int i = blockIdx.x * 256 + t;
    int v = (i < N) ? counts[i] : 0;
    tmp[t] = v;
    __syncthreads();
#pragma unroll
    for (int off = 1; off < 256; off <<= 1) {
        int a = (t >= off) ? tmp[t - off] : 0;
        __syncthreads();
        tmp[t] += a;
        __syncthreads();
    }
    if (i < N) rowstart[i] = tmp[t] - v;          // exclusive within block
    if (t == 255) bsum[blockIdx.x] = tmp[255];    // block total
}

__global__ __launch_bounds__(512) void scan2(int* __restrict__ bsum) {
    __shared__ int tmp[512];
    int t = threadIdx.x;
    int v = (t < NBLK) ? bsum[t] : 0;
    tmp[t] = v;
    __syncthreads();
#pragma unroll
    for (int off = 1; off < 512; off <<= 1) {
        int a = (t >= off) ? tmp[t - off] : 0;
        __syncthreads();
        tmp[t] += a;
        __syncthreads();
    }
    if (t < NBLK) bsum[t] = tmp[t] - v;           // exclusive block offsets
}

__global__ void scan3(int* __restrict__ rowstart, const int* __restrict__ bsum,
                      int* __restrict__ cursor) {
    int i = blockIdx.x * blockDim.x + threadIdx.x;
    if (i < N) {
        rowstart[i] += bsum[i >> 8];
        cursor[i] = 0;                            // counts recycled as cursor
    }
    if (i == 0) rowstart[N] = E;
}

// Dst-chunked CSR fill, XCD-aligned (chunk = blockIdx & 7) with non-temporal
// edge-stream loads so the chunk's csr write window stays L2-resident.
__global__ __launch_bounds__(256) void fill_csr_chunked(
        const int* __restrict__ raw, const int* __restrict__ flag,
        const int* __restrict__ rowstart, int* __restrict__ cursor,
        int* __restrict__ csr) {
    const int chunk = blockIdx.x & (NCHUNK - 1);
    const int bsl   = blockIdx.x >> 3;
    const int lo = chunk * CHUNK_N, hi = lo + CHUNK_N;
    const int is32 = *flag;
    for (int e = bsl * 256 + threadIdx.x; e < E; e += BPC * 256) {
        int d = is32 ? __builtin_nontemporal_load(&raw[E + e])
                     : __builtin_nontemporal_load(&raw[2 * ((long long)E + e)]);
        if (d < lo || d >= hi) continue;
        int s = is32 ? __builtin_nontemporal_load(&raw[e])
                     : __builtin_nontemporal_load(&raw[2 * (long long)e]);
        int pos = rowstart[d] + atomicAdd(&cursor[d], 1);
        csr[pos] = s;
    }
}

// ---------------- layer 1 transform (MFMA): z1(bf16) = x@W1l^T, r1(f32) = x@W1r^T ----------------
__global__ __launch_bounds__(256) void transform1_mfma(
        const float* __restrict__ x, const float* __restrict__ W1l,
        const float* __restrict__ W1r, unsigned short* __restrict__ z1b,
        float* __restrict__ r1) {
    const int lane = threadIdx.x & 63;
    const int gw = blockIdx.x * 4 + (threadIdx.x >> 6);
    const int q = gw & 1;
    const int r16 = lane & 15;
    const int kgrp = lane >> 4;                  // 0..3

    bf16x8 wf[2][2][4];                          // [mat][coltile][kb]
#pragma unroll
    for (int m = 0; m < 2; ++m) {
        const float* W = m ? W1r : W1l;
#pragma unroll
        for (int c = 0; c < 2; ++c) {
            const float* pw = W + (size_t)(q * 32 + c * 16 + r16) * 128 + kgrp * 8;
#pragma unroll
            for (int kb = 0; kb < 4; ++kb)
                wf[m][c][kb] = load_frag8(pw + kb * 32);
        }
    }

    const int stride = (gridDim.x * 4) >> 1;
    for (int t = gw >> 1; t < NT16; t += stride) {
        const float* px = x + ((size_t)t * 16 + r16) * 128 + kgrp * 8;
        bf16x8 af[4];
#pragma unroll
        for (int kb = 0; kb < 4; ++kb) af[kb] = load_frag8(px + kb * 32);

        f32x4 a00 = {0.f,0.f,0.f,0.f}, a01 = {0.f,0.f,0.f,0.f};
        f32x4 a10 = {0.f,0.f,0.f,0.f}, a11 = {0.f,0.f,0.f,0.f};
#pragma unroll
        for (int kb = 0; kb < 4; ++kb) {
            a00 = __builtin_amdgcn_mfma_f32_16x16x32_bf16(af[kb], wf[0][0][kb], a00, 0, 0, 0);
            a01 = __builtin_amdgcn_mfma_f32_16x16x32_bf16(af[kb], wf[0][1][kb], a01, 0, 0, 0);
            a10 = __builtin_amdgcn_mfma_f32_16x16x32_bf16(af[kb], wf[1][0][kb], a10, 0, 0, 0);
            a11 = __builtin_amdgcn_mfma_f32_16x16x32_bf16(af[kb], wf[1][1][kb], a11, 0, 0, 0);
        }
#pragma unroll
        for (int i = 0; i < 4; ++i) {
            size_t row = (size_t)t * 16 + kgrp * 4 + i;
            z1b[row * 64 + q * 32 +  0 + r16] = (unsigned short)f2bf(a00[i]);
            z1b[row * 64 + q * 32 + 16 + r16] = (unsigned short)f2bf(a01[i]);
            r1[row * 64 + q * 32 +  0 + r16] = a10[i];
            r1[row * 64 + q * 32 + 16 + r16] = a11[i];
        }
    }
}

// ---------------- layer 2 transform (MFMA): z2(bf16) = h@W2l^T, r2(f32) = h@W2r^T ----------------
__global__ __launch_bounds__(256) void transform2_mfma(
        const float* __restrict__ h, const float* __restrict__ W2l,
        const float* __restrict__ W2r, unsigned short* __restrict__ z2b,
        float* __restrict__ r2) {
    const int lane = threadIdx.x & 63;
    const int gw = blockIdx.x * 4 + (threadIdx.x >> 6);
    const int r16 = lane & 15;
    const int kgrp = lane >> 4;

    bf16x8 wf[2][2][2];                          // [mat][coltile][kb]
#pragma unroll
    for (int m = 0; m < 2; ++m) {
        const float* W = m ? W2r : W2l;
#pragma unroll
        for (int c = 0; c < 2; ++c) {
            const float* pw = W + (size_t)(c * 16 + r16) * 64 + kgrp * 8;
#pragma unroll
            for (int kb = 0; kb < 2; ++kb)
                wf[m][c][kb] = load_frag8(pw + kb * 32);
        }
    }

    for (int t = gw; t < NT16; t += gridDim.x * 4) {
        const float* ph = h + ((size_t)t * 16 + r16) * 64 + kgrp * 8;
        bf16x8 af[2];
        af[0] = load_frag8(ph);
        af[1] = load_frag8(ph + 32);

        f32x4 a00 = {0.f,0.f,0.f,0.f}, a01 = {0.f,0.f,0.f,0.f};
        f32x4 a10 = {0.f,0.f,0.f,0.f}, a11 = {0.f,0.f,0.f,0.f};
#pragma unroll
        for (int kb = 0; kb < 2; ++kb) {
            a00 = __builtin_amdgcn_mfma_f32_16x16x32_bf16(af[kb], wf[0][0][kb], a00, 0, 0, 0);
            a01 = __builtin_amdgcn_mfma_f32_16x16x32_bf16(af[kb], wf[0][1][kb], a01, 0, 0, 0);
            a10 = __builtin_amdgcn_mfma_f32_16x16x32_bf16(af[kb], wf[1][0][kb], a10, 0, 0, 0);
            a11 = __builtin_amdgcn_mfma_f32_16x16x32_bf16(af[kb], wf[1][1][kb], a11, 0, 0, 0);
        }
#pragma unroll
        for (int i = 0; i < 4; ++i) {
            size_t row = (size_t)t * 16 + kgrp * 4 + i;
            z2b[row * 32 +  0 + r16] = (unsigned short)f2bf(a00[i]);
            z2b[row * 32 + 16 + r16] = (unsigned short)f2bf(a01[i]);
            r2[row * 32 +  0 + r16] = a10[i];
            r2[row * 32 + 16 + r16] = a11[i];
        }
    }
}

// ---------------- fused CSR-gather aggregation ----------------

// Layer 1: wave per node, lane = feature j (64 feats), bf16 z gather.
__global__ __launch_bounds__(256) void agg1_fused(
        const int* __restrict__ rowstart, const int* __restrict__ csr,
        const unsigned short* __restrict__ z1b, const float* __restrict__ r1,
        const float* __restrict__ b1, float* __restrict__ h) {
    const int n = blockIdx.x * 4 + (threadIdx.x >> 6);
    if (n >= N) return;
    const int j = threadIdx.x & 63;
    const int beg = rowstart[n], end = rowstart[n + 1];
    float s = 0.f;
    int p = beg;
    for (; p + 4 <= end; p += 4) {
        int c0 = csr[p], c1 = csr[p + 1], c2 = csr[p + 2], c3 = csr[p + 3];
        s += bf2f(z1b[(size_t)c0 * 64 + j]) + bf2f(z1b[(size_t)c1 * 64 + j])
           + bf2f(z1b[(size_t)c2 * 64 + j]) + bf2f(z1b[(size_t)c3 * 64 + j]);
    }
    for (; p < end; ++p) s += bf2f(z1b[(size_t)csr[p] * 64 + j]);
    float m = (end > beg) ? s / (float)(end - beg) : 0.f;
    size_t o = (size_t)n * 64 + j;
    h[o] = fmaxf(m + b1[j] + r1[o], 0.f);
}

// Layer 2: half-wave per node (32 feats), wave handles 2 nodes.
__global__ __launch_bounds__(256) void agg2_fused(
        const int* __restrict__ rowstart, const int* __restrict__ csr,
        const unsigned short* __restrict__ z2b, const float* __restrict__ r2,
        const float* __restrict__ b2, float* __restrict__ out) {
    const int wid = blockIdx.x * 4 + (threadIdx.x >> 6);
    const int n = wid * 2 + ((threadIdx.x >> 5) & 1);
    if (n >= N) return;
    const int j = threadIdx.x & 31;
    const int beg = rowstart[n], end = rowstart[n + 1];
    float s = 0.f;
    int p = beg;
    for (; p + 4 <= end; p += 4) {
        int c0 = csr[p], c1 = csr[p + 1], c2 = csr[p + 2], c3 = csr[p + 3];
        s += bf2f(z2b[(size_t)c0 * 32 + j]) + bf2f(z2b[(size_t)c1 * 32 + j])
           + bf2f(z2b[(size_t)c2 * 32 + j]) + bf2f(z2b[(size_t)c3 * 32 + j]);
    }
    for (; p < end; ++p) s += bf2f(z2b[(size_t)csr[p] * 32 + j]);
    float m = (end > beg) ? s / (float)(end - beg) : 0.f;
    size_t o = (size_t)n * 32 + j;
    out[o] = m + b2[j] + r2[o];
}

// ---------------- launch ----------------

extern "C" void kernel_launch(void* const* d_in, const int* in_sizes, int n_in,
                              void* d_out, int out_size, void* d_ws, size_t ws_size,
                              hipStream_t stream) {
    const float* x    = (const float*)d_in[0];
    const int*   raw  = (const int*)d_in[1];
    const float* W1l  = (const float*)d_in[2];
    const float* b1   = (const float*)d_in[3];
    const float* W1r  = (const float*)d_in[4];
    const float* W2l  = (const float*)d_in[5];
    const float* b2   = (const float*)d_in[6];
    const float* W2r  = (const float*)d_in[7];
    float* out = (float*)d_out;

    // byte-offset workspace layout
    char* wsb = (char*)d_ws;
    unsigned short* z1b = (unsigned short*)wsb;              // [N*64] bf16 (12.8MB)
    unsigned short* z2b = (unsigned short*)wsb;              // [N*32] overlays z1b
    float* r1 = (float*)(wsb + 16 * 1024 * 1024);            // [N*64] f32 (25.6MB)
    float* r2 = (float*)(wsb + 16 * 1024 * 1024);            // [N*32] overlays r1
    float* h  = (float*)(wsb + 48 * 1024 * 1024);            // [N*64] f32 (25.6MB)

    int* ibase    = (int*)(wsb + 80 * 1024 * 1024);
    int* counts   = ibase;                   // [N], recycled as cursor
    int* rowstart = ibase + N;               // [N+1]
    int* bsum     = ibase + 2 * N + 1;       // [512]
    int* csr      = ibase + 2 * N + 1 + 512; // [E]
    int* flag     = csr + E;                 // [1]

    const int eb = (E + 255) / 256;

    detect_dtype<<<1, 256, 0, stream>>>(raw, flag);
    zero_counts<<<NBLK, 256, 0, stream>>>(counts);
    count_deg<<<eb, 256, 0, stream>>>(raw, flag, counts);
    scan1<<<NBLK, 256, 0, stream>>>(counts, rowstart, bsum);
    scan2<<<1, 512, 0, stream>>>(bsum);
    scan3<<<NBLK, 256, 0, stream>>>(rowstart, bsum, counts);
    fill_csr_chunked<<<NCHUNK * BPC, 256, 0, stream>>>(raw, flag, rowstart, counts, csr);

    transform1_mfma<<<1024, 256, 0, stream>>>(x, W1l, W1r, z1b, r1);
    agg1_fused<<<(N + 3) / 4, 256, 0, stream>>>(rowstart, csr, z1b, r1, b1, h);

    transform2_mfma<<<1024, 256, 0, stream>>>(h, W2l, W2r, z2b, r2);
    agg2_fused<<<(N + 7) / 8, 256, 0, stream>>>(rowstart, csr, z2b, r2, b2, out);
}